// Round 4
// baseline (123.519 us; speedup 1.0000x reference)
//
#include <hip/hip_runtime.h>
#include <hip/hip_cooperative_groups.h>
#include <math.h>

namespace cg = cooperative_groups;

#define N 1024
#define D 128
#define MAXNORM 0.996f
#define MINN 1e-15f

__device__ __forceinline__ float wave_sum(float v) {
#pragma unroll
    for (int o = 32; o > 0; o >>= 1) v += __shfl_xor(v, o, 64);
    return v;
}

__device__ __forceinline__ float artanh_fast(float x) {
    x = fminf(fmaxf(x, -1.0f + 1e-7f), 1.0f - 1e-7f);
    return 0.5f * __logf(__fdividef(1.0f + x, 1.0f - x));
}

__global__ __launch_bounds__(256, 4) void k_fused(
    const float* __restrict__ x, const float* __restrict__ adj,
    const float* __restrict__ Wm, const float* __restrict__ bias,
    const float* __restrict__ attw, const float* __restrict__ attb_p,
    float* __restrict__ h, float* __restrict__ h2a, float* __restrict__ sLa,
    float* __restrict__ sRa, float* __restrict__ out) {
    __shared__ float smv[D];
    __shared__ float his[D];
    __shared__ float sc_h2, sc_sL;
    __shared__ int lst[N];
    __shared__ int wcnt[4];
    __shared__ float accS[4][D];
    __shared__ float sAs[4];

    const int t = threadIdx.x, w = t >> 6, l = t & 63;
    const int i = blockIdx.x;
    const unsigned long long lt_mask = (1ull << l) - 1ull;

    // issue adj-row segment load early (hide HBM latency under phase 1)
    float4 av = *(const float4*)(adj + (size_t)i * N + (w << 8) + 4 * l);

    // ---- phase 1: mv = W @ x_i ; wave w computes outputs [32w, 32w+32)
    float2 xv = *(const float2*)(x + (size_t)i * D + 2 * l);
    float xn2 = wave_sum(xv.x * xv.x + xv.y * xv.y);
    float mymv = 0.f;
#pragma unroll 8
    for (int oo = 0; oo < 32; ++oo) {
        float2 wr = *(const float2*)(Wm + (size_t)((w << 5) + oo) * D + 2 * l);
        float s = wave_sum(wr.x * xv.x + wr.y * xv.y);
        if (l == oo) mymv = s;
    }
    if (l < 32) smv[(w << 5) + l] = mymv;

    // ---- adj compaction (deterministic order: wave, then element, then lane)
    float ae[4] = {av.x, av.y, av.z, av.w};
    unsigned long long msk[4];
    int cnt = 0;
#pragma unroll
    for (int e = 0; e < 4; ++e) {
        msk[e] = __ballot(ae[e] != 0.0f);
        cnt += __popcll(msk[e]);
    }
    if (l == 0) wcnt[w] = cnt;
    __syncthreads();

    int base = 0;
#pragma unroll
    for (int ww = 0; ww < 4; ++ww)
        if (ww < w) base += wcnt[ww];
    const int tot = wcnt[0] + wcnt[1] + wcnt[2] + wcnt[3];
    {
        int off = base;
#pragma unroll
        for (int e = 0; e < 4; ++e) {
            if (ae[e] != 0.0f) {
                int pos = __popcll(msk[e] & lt_mask);
                lst[off + pos] = (w << 8) + 4 * l + e;
            }
            off += __popcll(msk[e]);
        }
    }

    // ---- wave 0: scalar chain (bias, matvec scaling, mobius add, proj, att dots)
    if (w == 0) {
        float2 bv = *(const float2*)(bias + 2 * l);
        float bn2 = wave_sum(bv.x * bv.x + bv.y * bv.y);
        float bn = fmaxf(sqrtf(bn2), MINN);
        float tb = tanhf(bn);
        float bs = tb / bn;
        float2 hbv = make_float2(bs * bv.x, bs * bv.y);
        float vn = tb;  // |expmap0(bias)| = tanh(|bias|)
        if (vn > MAXNORM) {
            float sc0 = MAXNORM / vn;
            hbv.x *= sc0; hbv.y *= sc0;
            vn = MAXNORM;
        }
        float y2 = vn * vn;

        float2 mv = *(const float2*)(&smv[2 * l]);
        float mxn2 = wave_sum(mv.x * mv.x + mv.y * mv.y);
        float mxn = fmaxf(sqrtf(mxn2), MINN);
        float xn = fmaxf(sqrtf(xn2), MINN);
        float rn = tanhf(mxn / xn * artanh_fast(xn));  // = |mobius_matvec| >= 0
        float sc = rn / mxn;
        float r0 = sc * mv.x, r1 = sc * mv.y;
        float sr = (rn > MAXNORM) ? (MAXNORM / rn) : 1.f;
        r0 *= sr; r1 *= sr;
        float rn_c = rn * sr;
        float x2 = rn_c * rn_c;

        float xy = wave_sum(r0 * hbv.x + r1 * hbv.y);
        float den = fmaxf(1.f + 2.f * xy + x2 * y2, MINN);
        float ca = (1.f + 2.f * xy + y2) / den;
        float cb = (1.f - x2) / den;
        float hp0 = ca * r0 + cb * hbv.x;
        float hp1 = ca * r1 + cb * hbv.y;
        float hn2 = wave_sum(hp0 * hp0 + hp1 * hp1);
        float hn = fmaxf(sqrtf(hn2), MINN);
        float sh = (hn > MAXNORM) ? (MAXNORM / hn) : 1.f;
        hp0 *= sh; hp1 *= sh;
        float h2 = hn2 * sh * sh;

        float hnn = fmaxf(sqrtf(h2), MINN);
        float fac = artanh_fast(hnn) / hnn;
        float dwl = wave_sum(hp0 * attw[2 * l] + hp1 * attw[2 * l + 1]);
        float dwr = wave_sum(hp0 * attw[D + 2 * l] + hp1 * attw[D + 2 * l + 1]);

        *(float2*)(h + (size_t)i * D + 2 * l) = make_float2(hp0, hp1);
        *(float2*)(&his[2 * l]) = make_float2(hp0, hp1);
        if (l == 0) {
            h2a[i] = h2;
            sLa[i] = fac * dwl;
            sRa[i] = fac * dwr;
            sc_h2 = h2;
            sc_sL = fac * dwl;
        }
    }

    cg::this_grid().sync();

    // ---- phase 2: sparse aggregation over neighbor list
    float2 hi = *(const float2*)(&his[2 * l]);
    const float h2_i = sc_h2;
    const float sL_i = sc_sL;
    const float attb = attb_p[0];
    const float B = 1.f - h2_i;
    const float cA = fmaxf(B, MINN);

    float sAcc = 0.f, accB0 = 0.f, accB1 = 0.f;
    for (int n = w; n < tot; n += 4) {
        const int j = lst[n];
        float2 hj = *(const float2*)(h + (size_t)j * D + 2 * l);
        float aval = adj[(size_t)i * N + j];
        float h2_j = h2a[j];
        float sR_j = sRa[j];
        float dot = wave_sum(hi.x * hj.x + hi.y * hj.y);
        float den = fmaxf(1.f - 2.f * dot + h2_i * h2_j, MINN);
        float p = __fdividef(-(1.f - 2.f * dot + h2_j), den);
        float q = __fdividef(B, den);
        float n2 = p * p * h2_i + 2.f * p * q * dot + q * q * h2_j;
        float nrm = fmaxf(sqrtf(fmaxf(n2, 0.f)), MINN);
        float coefc = cA * __fdividef(artanh_fast(nrm), nrm);
        float sig = __fdividef(1.f, 1.f + __expf(-(sL_i + sR_j + attb)));
        float wgt = aval * sig;
        sAcc += wgt * coefc * p;
        float wb = wgt * coefc * q;
        accB0 += wb * hj.x;
        accB1 += wb * hj.y;
    }

    accS[w][2 * l] = accB0;
    accS[w][2 * l + 1] = accB1;
    if (l == 0) sAs[w] = sAcc;
    __syncthreads();

    if (w != 0) return;

    float b0 = accS[0][2 * l] + accS[1][2 * l] + accS[2][2 * l] + accS[3][2 * l];
    float b1 = accS[0][2 * l + 1] + accS[1][2 * l + 1] + accS[2][2 * l + 1] +
               accS[3][2 * l + 1];
    float sA = sAs[0] + sAs[1] + sAs[2] + sAs[3];

    float u0 = sA * hi.x + b0, u1 = sA * hi.y + b1;

    float u2 = wave_sum(u0 * u0 + u1 * u1);
    float un = fmaxf(sqrtf(u2), MINN);
    float lam = 2.f / cA;
    float th = tanhf(0.5f * lam * un);
    float s0 = th * u0 / un, s1 = th * u1 / un;
    float y2 = wave_sum(s0 * s0 + s1 * s1);
    float xy = wave_sum(hi.x * s0 + hi.y * s1);
    float den2 = fmaxf(1.f + 2.f * xy + h2_i * y2, MINN);
    float c1 = (1.f + 2.f * xy + y2) / den2;
    float c2 = (1.f - h2_i) / den2;
    float hp0 = c1 * hi.x + c2 * s0;
    float hp1 = c1 * hi.y + c2 * s1;
    float hn2 = wave_sum(hp0 * hp0 + hp1 * hp1);
    float hn = fmaxf(sqrtf(hn2), MINN);
    float scl = (hn > MAXNORM) ? (MAXNORM / hn) : 1.f;
    hp0 *= scl; hp1 *= scl;
    float n3 = fminf(fmaxf(hn, MINN), MAXNORM);
    float fac = tanhf(n3) / n3;
    float o0 = fac * hp0, o1 = fac * hp1;
    float onrm = tanhf(n3);
    if (onrm > MAXNORM) {
        float ss = MAXNORM / onrm;
        o0 *= ss; o1 *= ss;
    }
    *(float2*)(out + (size_t)i * D + 2 * l) = make_float2(o0, o1);
}

extern "C" void kernel_launch(void* const* d_in, const int* in_sizes, int n_in,
                              void* d_out, int out_size, void* d_ws, size_t ws_size,
                              hipStream_t stream) {
    const float* x = (const float*)d_in[0];
    const float* adj = (const float*)d_in[1];
    const float* Wm = (const float*)d_in[2];
    const float* bias = (const float*)d_in[3];
    const float* attw = (const float*)d_in[4];
    const float* attb = (const float*)d_in[5];
    float* out = (float*)d_out;

    float* ws = (float*)d_ws;
    float* h = ws;                     // N*D
    float* h2a = h + (size_t)N * D;    // N
    float* sL = h2a + N;               // N
    float* sR = sL + N;                // N

    void* args[] = {(void*)&x,    (void*)&adj, (void*)&Wm, (void*)&bias,
                    (void*)&attw, (void*)&attb, (void*)&h,  (void*)&h2a,
                    (void*)&sL,   (void*)&sR,   (void*)&out};
    hipLaunchCooperativeKernel((const void*)k_fused, dim3(N), dim3(256), args,
                               0, stream);
}

// Round 5
// 22.104 us; speedup vs baseline: 5.5882x; 5.5882x over previous
//
#include <hip/hip_runtime.h>
#include <math.h>

#define N 1024
#define D 128
#define MAXNORM 0.996f
#define MINN 1e-15f

__device__ __forceinline__ float wave_sum(float v) {
#pragma unroll
    for (int o = 32; o > 0; o >>= 1) v += __shfl_xor(v, o, 64);
    return v;
}

__device__ __forceinline__ float group16_sum(float v) {
#pragma unroll
    for (int o = 8; o > 0; o >>= 1) v += __shfl_xor(v, o, 64);
    return v;
}

__device__ __forceinline__ float artanh_fast(float x) {
    x = fminf(fmaxf(x, -1.0f + 1e-7f), 1.0f - 1e-7f);
    return 0.5f * __logf(__fdividef(1.0f + x, 1.0f - x));
}

// ---- kernel A: one block (4 waves) per row i -> h, h2, sL, sR
__global__ __launch_bounds__(256) void k_rows(
    const float* __restrict__ x, const float* __restrict__ Wm,
    const float* __restrict__ bias, const float* __restrict__ attw,
    float* __restrict__ h, float* __restrict__ h2a, float* __restrict__ sLa,
    float* __restrict__ sRa) {
    __shared__ float smv[D];
    const int t = threadIdx.x, w = t >> 6, l = t & 63;
    const int g = l >> 4, m = l & 15;  // 4 groups of 16 lanes per wave
    const int i = blockIdx.x;

    // x-row chunks for this lane's column slots (reused across all passes)
    float4 xa = *(const float4*)(x + (size_t)i * D + 4 * m);
    float4 xb = *(const float4*)(x + (size_t)i * D + 64 + 4 * m);

    // |x|^2: per-lane partial covers distinct k within a 16-lane group
    float xn2 = group16_sum(xa.x * xa.x + xa.y * xa.y + xa.z * xa.z +
                            xa.w * xa.w + xb.x * xb.x + xb.y * xb.y +
                            xb.z * xb.z + xb.w * xb.w);

    // matvec: wave w covers outputs [32w, 32w+32); group g does output 32w+4p+g
#pragma unroll
    for (int p = 0; p < 8; ++p) {
        const int o = (w << 5) + (p << 2) + g;
        float4 wa = *(const float4*)(Wm + (size_t)o * D + 4 * m);
        float4 wb = *(const float4*)(Wm + (size_t)o * D + 64 + 4 * m);
        float s = xa.x * wa.x + xa.y * wa.y + xa.z * wa.z + xa.w * wa.w +
                  xb.x * wb.x + xb.y * wb.y + xb.z * wb.z + xb.w * wb.w;
        s = group16_sum(s);
        if (m == 0) smv[o] = s;
    }
    __syncthreads();

    if (w != 0) return;

    // ---- wave 0: bias chain + mobius scalar chain
    float2 bv = *(const float2*)(bias + 2 * l);
    float bn2 = wave_sum(bv.x * bv.x + bv.y * bv.y);
    float bn = fmaxf(sqrtf(bn2), MINN);
    float tb = tanhf(bn);
    float bs = tb / bn;
    float2 hbv = make_float2(bs * bv.x, bs * bv.y);
    float vn = tb;  // |expmap0(bias)| = tanh(|bias|)
    if (vn > MAXNORM) {
        float sc0 = MAXNORM / vn;
        hbv.x *= sc0; hbv.y *= sc0;
        vn = MAXNORM;
    }
    float y2 = vn * vn;

    float2 mv = *(const float2*)(&smv[2 * l]);
    float mxn2 = wave_sum(mv.x * mv.x + mv.y * mv.y);
    float mxn = fmaxf(sqrtf(mxn2), MINN);
    float xn = fmaxf(sqrtf(xn2), MINN);
    float rn = tanhf(mxn / xn * artanh_fast(xn));  // = |mobius_matvec| >= 0
    float sc = rn / mxn;
    float r0 = sc * mv.x, r1 = sc * mv.y;
    float sr = (rn > MAXNORM) ? (MAXNORM / rn) : 1.f;
    r0 *= sr; r1 *= sr;
    float rn_c = rn * sr;
    float x2 = rn_c * rn_c;

    float xy = wave_sum(r0 * hbv.x + r1 * hbv.y);
    float den = fmaxf(1.f + 2.f * xy + x2 * y2, MINN);
    float ca = (1.f + 2.f * xy + y2) / den;
    float cb = (1.f - x2) / den;
    float hp0 = ca * r0 + cb * hbv.x;
    float hp1 = ca * r1 + cb * hbv.y;
    float hn2 = wave_sum(hp0 * hp0 + hp1 * hp1);
    float hn = fmaxf(sqrtf(hn2), MINN);
    float sh = (hn > MAXNORM) ? (MAXNORM / hn) : 1.f;
    hp0 *= sh; hp1 *= sh;
    float h2 = hn2 * sh * sh;

    float hnn = fmaxf(sqrtf(h2), MINN);
    float fac = artanh_fast(hnn) / hnn;
    float dwl = wave_sum(hp0 * attw[2 * l] + hp1 * attw[2 * l + 1]);
    float dwr = wave_sum(hp0 * attw[D + 2 * l] + hp1 * attw[D + 2 * l + 1]);

    *(float2*)(h + (size_t)i * D + 2 * l) = make_float2(hp0, hp1);
    if (l == 0) {
        h2a[i] = h2;
        sLa[i] = fac * dwl;
        sRa[i] = fac * dwr;
    }
}

// ---- kernel B: sparse aggregation + epilogue. One block (4 waves) per row i.
__global__ __launch_bounds__(256) void k_agg(const float* __restrict__ h,
                                             const float* __restrict__ h2a,
                                             const float* __restrict__ sLa,
                                             const float* __restrict__ sRa,
                                             const float* __restrict__ adj,
                                             const float* __restrict__ attb_p,
                                             float* __restrict__ out) {
    __shared__ int lst[N];
    __shared__ float vals[N];
    __shared__ int wcnt[4];
    __shared__ float accS[4][D];
    __shared__ float sAs[4];

    const int t = threadIdx.x, w = t >> 6, l = t & 63;
    const int i = blockIdx.x;
    const unsigned long long lt_mask = (1ull << l) - 1ull;

    // scan this wave's 256-column segment of adj row i (coalesced float4)
    float4 av = *(const float4*)(adj + (size_t)i * N + (w << 8) + 4 * l);
    float ae[4] = {av.x, av.y, av.z, av.w};
    unsigned long long msk[4];
    int cnt = 0;
#pragma unroll
    for (int e = 0; e < 4; ++e) {
        msk[e] = __ballot(ae[e] != 0.0f);
        cnt += __popcll(msk[e]);
    }
    if (l == 0) wcnt[w] = cnt;
    __syncthreads();

    int base = 0;
#pragma unroll
    for (int ww = 0; ww < 4; ++ww)
        if (ww < w) base += wcnt[ww];
    const int tot = wcnt[0] + wcnt[1] + wcnt[2] + wcnt[3];
    {
        int off = base;
#pragma unroll
        for (int e = 0; e < 4; ++e) {
            if (ae[e] != 0.0f) {
                int pos = __popcll(msk[e] & lt_mask);
                lst[off + pos] = (w << 8) + 4 * l + e;
                vals[off + pos] = ae[e];
            }
            off += __popcll(msk[e]);
        }
    }
    __syncthreads();

    float2 hi = *(const float2*)(h + (size_t)i * D + 2 * l);
    const float h2_i = h2a[i];
    const float sL_i = sLa[i];
    const float attb = attb_p[0];
    const float B = 1.f - h2_i;
    const float cA = fmaxf(B, MINN);

    float sAcc = 0.f, accB0 = 0.f, accB1 = 0.f;
    for (int n = w; n < tot; n += 4) {
        const int j = lst[n];
        float aval = vals[n];
        float2 hj = *(const float2*)(h + (size_t)j * D + 2 * l);
        float h2_j = h2a[j];
        float sR_j = sRa[j];
        float dot = wave_sum(hi.x * hj.x + hi.y * hj.y);
        float den = fmaxf(1.f - 2.f * dot + h2_i * h2_j, MINN);
        float p = __fdividef(-(1.f - 2.f * dot + h2_j), den);
        float q = __fdividef(B, den);
        float n2 = p * p * h2_i + 2.f * p * q * dot + q * q * h2_j;
        float nrm = fmaxf(sqrtf(fmaxf(n2, 0.f)), MINN);
        float coefc = cA * __fdividef(artanh_fast(nrm), nrm);
        float sig = __fdividef(1.f, 1.f + __expf(-(sL_i + sR_j + attb)));
        float wgt = aval * sig;
        sAcc += wgt * coefc * p;
        float wb = wgt * coefc * q;
        accB0 += wb * hj.x;
        accB1 += wb * hj.y;
    }

    accS[w][2 * l] = accB0;
    accS[w][2 * l + 1] = accB1;
    if (l == 0) sAs[w] = sAcc;
    __syncthreads();

    if (w != 0) return;

    float b0 = accS[0][2 * l] + accS[1][2 * l] + accS[2][2 * l] + accS[3][2 * l];
    float b1 = accS[0][2 * l + 1] + accS[1][2 * l + 1] + accS[2][2 * l + 1] +
               accS[3][2 * l + 1];
    float sA = sAs[0] + sAs[1] + sAs[2] + sAs[3];

    float u0 = sA * hi.x + b0, u1 = sA * hi.y + b1;

    float u2 = wave_sum(u0 * u0 + u1 * u1);
    float un = fmaxf(sqrtf(u2), MINN);
    float lam = 2.f / cA;
    float th = tanhf(0.5f * lam * un);
    float s0 = th * u0 / un, s1 = th * u1 / un;
    float y2 = wave_sum(s0 * s0 + s1 * s1);
    float xy = wave_sum(hi.x * s0 + hi.y * s1);
    float den2 = fmaxf(1.f + 2.f * xy + h2_i * y2, MINN);
    float c1 = (1.f + 2.f * xy + y2) / den2;
    float c2 = (1.f - h2_i) / den2;
    float hp0 = c1 * hi.x + c2 * s0;
    float hp1 = c1 * hi.y + c2 * s1;
    float hn2 = wave_sum(hp0 * hp0 + hp1 * hp1);
    float hn = fmaxf(sqrtf(hn2), MINN);
    float scl = (hn > MAXNORM) ? (MAXNORM / hn) : 1.f;
    hp0 *= scl; hp1 *= scl;
    float n3 = fminf(fmaxf(hn, MINN), MAXNORM);
    float fac = tanhf(n3) / n3;
    float o0 = fac * hp0, o1 = fac * hp1;
    float onrm = tanhf(n3);
    if (onrm > MAXNORM) {
        float ss = MAXNORM / onrm;
        o0 *= ss; o1 *= ss;
    }
    *(float2*)(out + (size_t)i * D + 2 * l) = make_float2(o0, o1);
}

extern "C" void kernel_launch(void* const* d_in, const int* in_sizes, int n_in,
                              void* d_out, int out_size, void* d_ws, size_t ws_size,
                              hipStream_t stream) {
    const float* x = (const float*)d_in[0];
    const float* adj = (const float*)d_in[1];
    const float* Wm = (const float*)d_in[2];
    const float* bias = (const float*)d_in[3];
    const float* attw = (const float*)d_in[4];
    const float* attb = (const float*)d_in[5];
    float* out = (float*)d_out;

    float* ws = (float*)d_ws;
    float* h = ws;                     // N*D
    float* h2a = h + (size_t)N * D;    // N
    float* sL = h2a + N;               // N
    float* sR = sL + N;                // N

    hipLaunchKernelGGL(k_rows, dim3(N), dim3(256), 0, stream, x, Wm, bias, attw,
                       h, h2a, sL, sR);
    hipLaunchKernelGGL(k_agg, dim3(N), dim3(256), 0, stream, h, h2a, sL, sR,
                       adj, attb, out);
}

// Round 6
// 17.746 us; speedup vs baseline: 6.9605x; 1.2456x over previous
//
#include <hip/hip_runtime.h>
#include <math.h>

#define N 1024
#define D 128
#define CAP 96
#define MAXNORM 0.996f
#define MINN 1e-15f

__device__ __forceinline__ float wave_sum(float v) {
#pragma unroll
    for (int o = 32; o > 0; o >>= 1) v += __shfl_xor(v, o, 64);
    return v;
}

__device__ __forceinline__ void wave_sum2(float& a, float& b) {
#pragma unroll
    for (int o = 32; o > 0; o >>= 1) {
        a += __shfl_xor(a, o, 64);
        b += __shfl_xor(b, o, 64);
    }
}

__device__ __forceinline__ float group16_sum(float v) {
#pragma unroll
    for (int o = 8; o > 0; o >>= 1) v += __shfl_xor(v, o, 64);
    return v;
}

__device__ __forceinline__ float artanh_fast(float x) {
    x = fminf(fmaxf(x, -1.0f + 1e-7f), 1.0f - 1e-7f);
    return 0.5f * __logf(__fdividef(1.0f + x, 1.0f - x));
}

// ---- kernel A: one block (4 waves) per row i.
// h, h2, sL, sR + adj-row compaction to CSR (cnt/lst/vals).
__global__ __launch_bounds__(256) void k_rows(
    const float* __restrict__ x, const float* __restrict__ Wm,
    const float* __restrict__ bias, const float* __restrict__ attw,
    const float* __restrict__ adj, float* __restrict__ h,
    float* __restrict__ h2a, float* __restrict__ sLa, float* __restrict__ sRa,
    int* __restrict__ cnt_g, int* __restrict__ lst_g,
    float* __restrict__ vals_g) {
    __shared__ float smv[D];
    __shared__ int wcnt[4];
    const int t = threadIdx.x, w = t >> 6, l = t & 63;
    const int g = l >> 4, m = l & 15;
    const int i = blockIdx.x;
    const unsigned long long lt_mask = (1ull << l) - 1ull;

    // issue adj-row segment load early (hide HBM latency under the matvec)
    float4 av = *(const float4*)(adj + (size_t)i * N + (w << 8) + 4 * l);

    // x-row chunks (reused across all 8 matvec passes)
    float4 xa = *(const float4*)(x + (size_t)i * D + 4 * m);
    float4 xb = *(const float4*)(x + (size_t)i * D + 64 + 4 * m);

    float xn2 = group16_sum(xa.x * xa.x + xa.y * xa.y + xa.z * xa.z +
                            xa.w * xa.w + xb.x * xb.x + xb.y * xb.y +
                            xb.z * xb.z + xb.w * xb.w);

    // matvec: wave w covers outputs [32w,32w+32); group g does output 32w+4p+g
#pragma unroll
    for (int p = 0; p < 8; ++p) {
        const int o = (w << 5) + (p << 2) + g;
        float4 wa = *(const float4*)(Wm + (size_t)o * D + 4 * m);
        float4 wb = *(const float4*)(Wm + (size_t)o * D + 64 + 4 * m);
        float s = xa.x * wa.x + xa.y * wa.y + xa.z * wa.z + xa.w * wa.w +
                  xb.x * wb.x + xb.y * wb.y + xb.z * wb.z + xb.w * wb.w;
        s = group16_sum(s);
        if (m == 0) smv[o] = s;
    }

    // ballot compaction bookkeeping (no barrier needed yet)
    float ae[4] = {av.x, av.y, av.z, av.w};
    unsigned long long msk[4];
    int cnt = 0;
#pragma unroll
    for (int e = 0; e < 4; ++e) {
        msk[e] = __ballot(ae[e] != 0.0f);
        cnt += __popcll(msk[e]);
    }
    if (l == 0) wcnt[w] = cnt;
    __syncthreads();  // publishes smv and wcnt

    int base = 0;
#pragma unroll
    for (int ww = 0; ww < 4; ++ww)
        if (ww < w) base += wcnt[ww];
    const int tot = wcnt[0] + wcnt[1] + wcnt[2] + wcnt[3];
    {
        int off = base;
#pragma unroll
        for (int e = 0; e < 4; ++e) {
            if (ae[e] != 0.0f) {
                int pos = off + __popcll(msk[e] & lt_mask);
                if (pos < CAP) {
                    lst_g[i * CAP + pos] = (w << 8) + 4 * l + e;
                    vals_g[i * CAP + pos] = ae[e];
                }
            }
            off += __popcll(msk[e]);
        }
    }
    if (t == 0) cnt_g[i] = (tot < CAP) ? tot : CAP;

    if (w != 0) return;

    // ---- wave 0: bias chain + mobius scalar chain (lane l owns dims 2l,2l+1)
    float2 bv = *(const float2*)(bias + 2 * l);
    float bn2 = wave_sum(bv.x * bv.x + bv.y * bv.y);
    float bn = fmaxf(sqrtf(bn2), MINN);
    float tb = tanhf(bn);
    float bs = tb / bn;
    float2 hbv = make_float2(bs * bv.x, bs * bv.y);
    float vn = tb;  // |expmap0(bias)| = tanh(|bias|)
    if (vn > MAXNORM) {
        float sc0 = MAXNORM / vn;
        hbv.x *= sc0; hbv.y *= sc0;
        vn = MAXNORM;
    }
    float y2 = vn * vn;

    float2 mv = *(const float2*)(&smv[2 * l]);
    float mxn2 = wave_sum(mv.x * mv.x + mv.y * mv.y);
    float mxn = fmaxf(sqrtf(mxn2), MINN);
    float xn = fmaxf(sqrtf(xn2), MINN);
    float rn = tanhf(mxn / xn * artanh_fast(xn));  // = |mobius_matvec| >= 0
    float sc = rn / mxn;
    float r0 = sc * mv.x, r1 = sc * mv.y;
    float sr = (rn > MAXNORM) ? (MAXNORM / rn) : 1.f;
    r0 *= sr; r1 *= sr;
    float rn_c = rn * sr;
    float x2 = rn_c * rn_c;

    float xy = wave_sum(r0 * hbv.x + r1 * hbv.y);
    float den = fmaxf(1.f + 2.f * xy + x2 * y2, MINN);
    float ca = (1.f + 2.f * xy + y2) / den;
    float cb = (1.f - x2) / den;
    float hp0 = ca * r0 + cb * hbv.x;
    float hp1 = ca * r1 + cb * hbv.y;
    float hn2 = wave_sum(hp0 * hp0 + hp1 * hp1);
    float hn = fmaxf(sqrtf(hn2), MINN);
    float sh = (hn > MAXNORM) ? (MAXNORM / hn) : 1.f;
    hp0 *= sh; hp1 *= sh;
    float h2 = hn2 * sh * sh;

    float hnn = fmaxf(sqrtf(h2), MINN);
    float fac = artanh_fast(hnn) / hnn;
    float dwl = wave_sum(hp0 * attw[2 * l] + hp1 * attw[2 * l + 1]);
    float dwr = wave_sum(hp0 * attw[D + 2 * l] + hp1 * attw[D + 2 * l + 1]);

    *(float2*)(h + (size_t)i * D + 2 * l) = make_float2(hp0, hp1);
    if (l == 0) {
        h2a[i] = h2;
        sLa[i] = fac * dwl;
        sRa[i] = fac * dwr;
    }
}

// ---- kernel B: sparse aggregation + epilogue. One block per row i.
// 16 groups of 16 lanes; group gid processes neighbors n = gid, gid+16, ...
// lane m of a group owns dims [8m, 8m+8).
__global__ __launch_bounds__(256) void k_agg(
    const float* __restrict__ h, const float* __restrict__ h2a,
    const float* __restrict__ sLa, const float* __restrict__ sRa,
    const int* __restrict__ cnt_g, const int* __restrict__ lst_g,
    const float* __restrict__ vals_g, const float* __restrict__ attb_p,
    float* __restrict__ out) {
    __shared__ float accS[16][132];
    __shared__ float sAs[16];

    const int t = threadIdx.x, w = t >> 6, l = t & 63;
    const int gid = t >> 4, m = t & 15;
    const int i = blockIdx.x;

    const int tot = cnt_g[i];
    const float h2_i = h2a[i];
    const float sL_i = sLa[i];
    const float attb = attb_p[0];
    const float B = 1.f - h2_i;
    const float cA = fmaxf(B, MINN);

    float4 hi0 = *(const float4*)(h + (size_t)i * D + 8 * m);
    float4 hi1 = *(const float4*)(h + (size_t)i * D + 8 * m + 4);

    float4 a0 = make_float4(0.f, 0.f, 0.f, 0.f);
    float4 a1 = make_float4(0.f, 0.f, 0.f, 0.f);
    float sAcc = 0.f;

    for (int n = gid; n < tot; n += 16) {
        const int j = lst_g[i * CAP + n];
        const float aval = vals_g[i * CAP + n];
        float4 hj0 = *(const float4*)(h + (size_t)j * D + 8 * m);
        float4 hj1 = *(const float4*)(h + (size_t)j * D + 8 * m + 4);
        float d = hi0.x * hj0.x + hi0.y * hj0.y + hi0.z * hj0.z +
                  hi0.w * hj0.w + hi1.x * hj1.x + hi1.y * hj1.y +
                  hi1.z * hj1.z + hi1.w * hj1.w;
        float dot = group16_sum(d);
        float h2_j = h2a[j];
        float sR_j = sRa[j];
        float den = fmaxf(1.f - 2.f * dot + h2_i * h2_j, MINN);
        float p = __fdividef(-(1.f - 2.f * dot + h2_j), den);
        float q = __fdividef(B, den);
        float n2 = p * p * h2_i + 2.f * p * q * dot + q * q * h2_j;
        float nrm = fmaxf(sqrtf(fmaxf(n2, 0.f)), MINN);
        float coefc = cA * __fdividef(artanh_fast(nrm), nrm);
        float sig = __fdividef(1.f, 1.f + __expf(-(sL_i + sR_j + attb)));
        float wgt = aval * sig;
        sAcc += wgt * coefc * p;
        float wb = wgt * coefc * q;
        a0.x += wb * hj0.x; a0.y += wb * hj0.y;
        a0.z += wb * hj0.z; a0.w += wb * hj0.w;
        a1.x += wb * hj1.x; a1.y += wb * hj1.y;
        a1.z += wb * hj1.z; a1.w += wb * hj1.w;
    }

    *(float4*)(&accS[gid][8 * m]) = a0;
    *(float4*)(&accS[gid][8 * m + 4]) = a1;
    if (m == 0) sAs[gid] = sAcc;
    __syncthreads();

    if (w != 0) return;

    // ---- wave 0 epilogue: lane l owns dims (2l, 2l+1)
    float b0 = 0.f, b1 = 0.f, sA = 0.f;
#pragma unroll
    for (int g2 = 0; g2 < 16; ++g2) {
        b0 += accS[g2][2 * l];
        b1 += accS[g2][2 * l + 1];
        sA += sAs[g2];
    }

    float2 hi = *(const float2*)(h + (size_t)i * D + 2 * l);
    float u0 = sA * hi.x + b0, u1 = sA * hi.y + b1;

    float u2 = u0 * u0 + u1 * u1;
    float hiu = hi.x * u0 + hi.y * u1;
    wave_sum2(u2, hiu);
    float un = fmaxf(sqrtf(u2), MINN);
    float lam = 2.f / cA;
    float th = tanhf(0.5f * lam * un);
    float r = th / un;
    float s0 = r * u0, s1 = r * u1;
    float y2 = th * th;
    float xy = r * hiu;
    float den2 = fmaxf(1.f + 2.f * xy + h2_i * y2, MINN);
    float c1 = (1.f + 2.f * xy + y2) / den2;
    float c2 = (1.f - h2_i) / den2;
    float hp0 = c1 * hi.x + c2 * s0;
    float hp1 = c1 * hi.y + c2 * s1;
    float hn2 = wave_sum(hp0 * hp0 + hp1 * hp1);
    float hn = fmaxf(sqrtf(hn2), MINN);
    float scl = (hn > MAXNORM) ? (MAXNORM / hn) : 1.f;
    hp0 *= scl; hp1 *= scl;
    float n3 = fminf(fmaxf(hn, MINN), MAXNORM);
    float fac = tanhf(n3) / n3;
    float o0 = fac * hp0, o1 = fac * hp1;
    float onrm = tanhf(n3);
    if (onrm > MAXNORM) {
        float ss = MAXNORM / onrm;
        o0 *= ss; o1 *= ss;
    }
    *(float2*)(out + (size_t)i * D + 2 * l) = make_float2(o0, o1);
}

extern "C" void kernel_launch(void* const* d_in, const int* in_sizes, int n_in,
                              void* d_out, int out_size, void* d_ws, size_t ws_size,
                              hipStream_t stream) {
    const float* x = (const float*)d_in[0];
    const float* adj = (const float*)d_in[1];
    const float* Wm = (const float*)d_in[2];
    const float* bias = (const float*)d_in[3];
    const float* attw = (const float*)d_in[4];
    const float* attb = (const float*)d_in[5];
    float* out = (float*)d_out;

    float* ws = (float*)d_ws;
    float* h = ws;                       // N*D
    float* h2a = h + (size_t)N * D;      // N
    float* sL = h2a + N;                 // N
    float* sR = sL + N;                  // N
    float* vals_g = sR + N;              // N*CAP
    int* cnt_g = (int*)(vals_g + (size_t)N * CAP);  // N
    int* lst_g = cnt_g + N;              // N*CAP

    hipLaunchKernelGGL(k_rows, dim3(N), dim3(256), 0, stream, x, Wm, bias, attw,
                       adj, h, h2a, sL, sR, cnt_g, lst_g, vals_g);
    hipLaunchKernelGGL(k_agg, dim3(N), dim3(256), 0, stream, h, h2a, sL, sR,
                       cnt_g, lst_g, vals_g, attb, out);
}